// Round 1
// baseline (178.980 us; speedup 1.0000x reference)
//
#include <hip/hip_runtime.h>
#include <hip/hip_bf16.h>

#define F 64
#define R 64
#define O 64
#define BLOCK_B 64

typedef short bf16x8 __attribute__((ext_vector_type(8)));
typedef float f32x4 __attribute__((ext_vector_type(4)));

static __device__ __forceinline__ short f2bf(float f) {
    unsigned u = __builtin_bit_cast(unsigned, f);
    unsigned r = (u + 0x7fffu + ((u >> 16) & 1u)) >> 16;
    return (short)r;
}

// ---------------------------------------------------------------------------
// Prep kernel: blocks 0..64 pack W (fp32) -> Wpk (bf16, MFMA B-fragment order)
//              block 65 computes prm[f*64+r] = {s, mn, t, c}  (float4)
//   s  = sqrt(log2(e)) / std          (folds exp->exp2 conversion)
//   mn = mean * s
//   t  = tanh(tt); c = 0.5*(1-t)
// Wpk flat u16 index: (((f*4 + nt)*2 + kk)*64 + lane)*8 + j
//   value = W[o = nt*16 + (lane&15)][f*64 + r],  r = (lane>>4)*8 + j + kk*32
// ---------------------------------------------------------------------------
__global__ __launch_bounds__(256) void fq_prep(
        const float* __restrict__ tt, const float* __restrict__ mean,
        const float* __restrict__ std_, const float* __restrict__ W,
        float* __restrict__ prm, unsigned short* __restrict__ Wpk)
{
    const int blk = blockIdx.x;
    const int t = threadIdx.x;
    if (blk < 65) {
        const int f = blk;
        for (int u = t; u < 4096; u += 256) {
            int j    = u & 7;
            int lane = (u >> 3) & 63;
            int kk   = (u >> 9) & 1;
            int nt   = (u >> 10) & 3;
            int o    = nt * 16 + (lane & 15);
            int r    = ((lane >> 4) << 3) + j + kk * 32;
            float wv = W[o * 4160 + f * 64 + r];
            Wpk[f * 4096 + u] = (unsigned short)f2bf(wv);
        }
    } else {
        for (int u = t; u < 4096; u += 256) {
            float sd = std_[u];
            float mn = mean[u];
            float th = tanhf(tt[u]);
            float s  = 1.2011224087864498f / sd;  // sqrt(log2(e)) / std
            float4 p;
            p.x = s;
            p.y = mn * s;
            p.z = th;
            p.w = 0.5f * (1.0f - th);
            ((float4*)prm)[u] = p;
        }
    }
}

// ---------------------------------------------------------------------------
// Main fused kernel: one block = 64 batch rows, 256 threads (4 waves).
// Stage 1: fire[b][r], lane = r, wave covers b in {wave, wave+4, ..., wave+60}
// Stage 2: out = sum_f diag(x_f) * (w @ B_f) via mfma_f32_16x16x32_bf16,
//          wave owns rows [16*wave, 16*wave+16), all 64 output cols.
// ---------------------------------------------------------------------------
__global__ __launch_bounds__(256) void fq_main(
        const float* __restrict__ X,
        const float4* __restrict__ prm,
        const bf16x8* __restrict__ Wp,
        float* __restrict__ out)
{
    __shared__ float fire_lds[BLOCK_B][R + 1];
    __shared__ float rinv[BLOCK_B];

    const int t    = threadIdx.x;
    const int lane = t & 63;
    const int wu   = __builtin_amdgcn_readfirstlane(t >> 6);  // wave id, uniform
    const int b0   = blockIdx.x * BLOCK_B;

    // ---------------- stage 1: firing strengths -----------------------------
    float fire[16];
#pragma unroll
    for (int i = 0; i < 16; ++i) fire[i] = 1.0f;

    for (int f = 0; f < F; ++f) {
        float4 p = prm[f * 64 + lane];  // {s, mn, t, c} for (f, r=lane)
#pragma unroll
        for (int i = 0; i < 16; ++i) {
            float x = X[(b0 + wu + 4 * i) * 64 + f];  // wave-uniform -> s_load
            float z = __builtin_fmaf(x, p.x, -p.y);
            float g = __builtin_amdgcn_exp2f(-(z * z));
            float m = __builtin_fmaf(g, p.z, p.w);
            fire[i] *= m;
        }
    }
#pragma unroll
    for (int i = 0; i < 16; ++i)
        fire_lds[wu + 4 * i][lane] = fire[i];
    __syncthreads();

    // row sums -> reciprocal (one wave)
    if (t < 64) {
        float s = 0.0f;
#pragma unroll 8
        for (int r = 0; r < 64; ++r) s += fire_lds[t][r];
        rinv[t] = 1.0f / s;
    }
    __syncthreads();

    // ---------------- stage 2: out = sum_f diag(x_f) * (w @ B_f) ------------
    const int m_in  = lane & 15;   // row within 16x16 tile
    const int quad  = lane >> 4;
    const int myrow = 16 * wu + m_in;      // local row for A-fragment
    const float rs  = rinv[myrow];

    bf16x8 wfrag[2];
#pragma unroll
    for (int kk = 0; kk < 2; ++kk) {
#pragma unroll
        for (int j = 0; j < 8; ++j) {
            float wv = fire_lds[myrow][quad * 8 + j + kk * 32] * rs;
            wfrag[kk][j] = f2bf(wv);
        }
    }

    f32x4 acc[4];
#pragma unroll
    for (int nt = 0; nt < 4; ++nt) acc[nt] = (f32x4){0.f, 0.f, 0.f, 0.f};

    const int xrow = b0 + 16 * wu + quad * 4;  // + reg gives the C/D row

    for (int f = 0; f < F; ++f) {
        bf16x8 bfr[4][2];
#pragma unroll
        for (int nt = 0; nt < 4; ++nt)
#pragma unroll
            for (int kk = 0; kk < 2; ++kk)
                bfr[nt][kk] = Wp[((f * 4 + nt) * 2 + kk) * 64 + lane];

        f32x4 U[4];
        const f32x4 z4 = (f32x4){0.f, 0.f, 0.f, 0.f};
#pragma unroll
        for (int nt = 0; nt < 4; ++nt) {
            U[nt] = __builtin_amdgcn_mfma_f32_16x16x32_bf16(wfrag[0], bfr[nt][0], z4, 0, 0, 0);
            U[nt] = __builtin_amdgcn_mfma_f32_16x16x32_bf16(wfrag[1], bfr[nt][1], U[nt], 0, 0, 0);
        }

        float xv[4];
#pragma unroll
        for (int reg = 0; reg < 4; ++reg)
            xv[reg] = X[(xrow + reg) * 64 + f];

#pragma unroll
        for (int nt = 0; nt < 4; ++nt)
#pragma unroll
            for (int reg = 0; reg < 4; ++reg)
                acc[nt][reg] = __builtin_fmaf(xv[reg], U[nt][reg], acc[nt][reg]);
    }

    // bias column f = F (Xa[:,64] = 1): acc += U
    {
        bf16x8 bfr[4][2];
#pragma unroll
        for (int nt = 0; nt < 4; ++nt)
#pragma unroll
            for (int kk = 0; kk < 2; ++kk)
                bfr[nt][kk] = Wp[((F * 4 + nt) * 2 + kk) * 64 + lane];
        const f32x4 z4 = (f32x4){0.f, 0.f, 0.f, 0.f};
#pragma unroll
        for (int nt = 0; nt < 4; ++nt) {
            f32x4 U;
            U = __builtin_amdgcn_mfma_f32_16x16x32_bf16(wfrag[0], bfr[nt][0], z4, 0, 0, 0);
            U = __builtin_amdgcn_mfma_f32_16x16x32_bf16(wfrag[1], bfr[nt][1], U, 0, 0, 0);
#pragma unroll
            for (int reg = 0; reg < 4; ++reg)
                acc[nt][reg] += U[reg];
        }
    }

    // epilogue: D[row][col], col = nt*16 + m_in, row = 16*wu + quad*4 + reg
#pragma unroll
    for (int nt = 0; nt < 4; ++nt)
#pragma unroll
        for (int reg = 0; reg < 4; ++reg) {
            int row = b0 + 16 * wu + quad * 4 + reg;
            int o   = nt * 16 + m_in;
            out[row * 64 + o] = acc[nt][reg];
        }
}

extern "C" void kernel_launch(void* const* d_in, const int* in_sizes, int n_in,
                              void* d_out, int out_size, void* d_ws, size_t ws_size,
                              hipStream_t stream) {
    const float* X    = (const float*)d_in[0];
    const float* tt   = (const float*)d_in[1];
    const float* mean = (const float*)d_in[2];
    const float* std_ = (const float*)d_in[3];
    const float* W    = (const float*)d_in[4];
    float* out = (float*)d_out;

    // workspace layout: prm (float4 x 4096 = 64 KiB) | Wpk (bf16 x 266240 = 520 KiB)
    float* prm = (float*)d_ws;
    unsigned short* Wpk = (unsigned short*)((char*)d_ws + 65536);

    fq_prep<<<66, 256, 0, stream>>>(tt, mean, std_, W, prm, Wpk);

    const int nblocks = 32768 / BLOCK_B;  // 512
    fq_main<<<nblocks, 256, 0, stream>>>(X, (const float4*)prm,
                                         (const bf16x8*)Wpk, out);
}

// Round 2
// 114.519 us; speedup vs baseline: 1.5629x; 1.5629x over previous
//
#include <hip/hip_runtime.h>
#include <hip/hip_bf16.h>

#define F 64
#define R 64
#define O 64
#define BLOCK_B 32   // batch rows per block (512 threads, 8 waves)

typedef short bf16x8 __attribute__((ext_vector_type(8)));
typedef float f32x4 __attribute__((ext_vector_type(4)));

static __device__ __forceinline__ short f2bf(float f) {
    unsigned u = __builtin_bit_cast(unsigned, f);
    unsigned r = (u + 0x7fffu + ((u >> 16) & 1u)) >> 16;
    return (short)r;
}

// ---------------------------------------------------------------------------
// Prep kernel (flat, 146 blocks x 256):
//   threads [0, 33280): pack W (fp32) -> Wpk (bf16, MFMA B-fragment order)
//     tg = f*512 + u8;  u8 = nt*128 + kk*64 + lane;  Wpk[tg*8 + j]
//     value = W[o*4160 + f*64 + r], o = nt*16+(lane&15), r = (lane>>4)*8+j+kk*32
//   threads [33280, 37376): prm[u] = {s, mn*s, t, c}, u = f*64 + r
//     s = sqrt(log2(e))/std  (folds exp->exp2)
// ---------------------------------------------------------------------------
__global__ __launch_bounds__(256) void fq_prep(
        const float* __restrict__ tt, const float* __restrict__ mean,
        const float* __restrict__ std_, const float* __restrict__ W,
        float* __restrict__ prm, unsigned short* __restrict__ Wpk)
{
    const int tg = blockIdx.x * 256 + threadIdx.x;
    if (tg < 65 * 512) {
        const int f    = tg >> 9;
        const int u8   = tg & 511;
        const int lane = u8 & 63;
        const int kk   = (u8 >> 6) & 1;
        const int nt   = u8 >> 7;
        const int o    = nt * 16 + (lane & 15);
        const int rb   = ((lane >> 4) << 3) + kk * 32;
        const float* src = W + o * 4160 + f * 64 + rb;
        unsigned short v[8];
#pragma unroll
        for (int j = 0; j < 8; ++j) v[j] = (unsigned short)f2bf(src[j]);
        // contiguous 16B store
        *(bf16x8*)(Wpk + (size_t)tg * 8) = *(bf16x8*)v;
    } else if (tg < 65 * 512 + 4096) {
        const int u = tg - 65 * 512;
        float sd = std_[u];
        float mn = mean[u];
        float th = tanhf(tt[u]);
        float s  = 1.2011224087864498f / sd;  // sqrt(log2(e)) / std
        float4 p;
        p.x = s;
        p.y = mn * s;
        p.z = th;
        p.w = 0.5f * (1.0f - th);
        ((float4*)prm)[u] = p;
    }
}

// ---------------------------------------------------------------------------
// Main fused kernel: block = 32 batch rows, 512 threads (8 waves).
// Stage 1: wave w computes fire for rows 4w..4w+3 (lane = rule r).
// Stage 2: wave w = (nt<<1)|mrow owns a 16x16 output tile:
//          rows [16*mrow,16*mrow+16) x cols [16*nt,16*nt+16),
//          out = sum_f diag(x_f) * (w @ B_f) via mfma_f32_16x16x32_bf16.
// ---------------------------------------------------------------------------
__global__ __launch_bounds__(512, 8) void fq_main(
        const float* __restrict__ X,
        const float4* __restrict__ prm,
        const bf16x8* __restrict__ Wp,
        float* __restrict__ out)
{
    __shared__ float xt[64][BLOCK_B];           // [f][row], transposed X slab
    __shared__ float fire_lds[BLOCK_B][R + 1];
    __shared__ float rinv[BLOCK_B];

    const int t    = threadIdx.x;
    const int lane = t & 63;
    const int w    = __builtin_amdgcn_readfirstlane(t >> 6);  // wave id 0..7
    const int b0   = blockIdx.x * BLOCK_B;

    // ---- fill xt (coalesced float4 read, transposed LDS write) -------------
    {
        const int row = t >> 4;           // 0..31
        const int f4  = (t & 15) * 4;     // 0..60
        float4 xv = *(const float4*)(X + (size_t)(b0 + row) * 64 + f4);
        xt[f4 + 0][row] = xv.x;
        xt[f4 + 1][row] = xv.y;
        xt[f4 + 2][row] = xv.z;
        xt[f4 + 3][row] = xv.w;
    }

    // ---- stage 1: firing strengths (lane = r, 4 rows per wave) -------------
    float fire[4] = {1.f, 1.f, 1.f, 1.f};
    for (int f = 0; f < F; ++f) {
        float4 p = prm[f * 64 + lane];    // {s, mn*s, t, c}
#pragma unroll
        for (int i = 0; i < 4; ++i) {
            float x = X[(size_t)(b0 + 4 * w + i) * 64 + f];  // uniform -> s_load
            float z = __builtin_fmaf(x, p.x, -p.y);
            float g = __builtin_amdgcn_exp2f(-(z * z));
            fire[i] *= __builtin_fmaf(g, p.z, p.w);
        }
    }
#pragma unroll
    for (int i = 0; i < 4; ++i)
        fire_lds[4 * w + i][lane] = fire[i];
    __syncthreads();

    if (t < BLOCK_B) {
        float s = 0.0f;
#pragma unroll 8
        for (int r = 0; r < 64; ++r) s += fire_lds[t][r];
        rinv[t] = 1.0f / s;
    }
    __syncthreads();

    // ---- stage 2: 16x16 tile per wave --------------------------------------
    const int m_in  = lane & 15;
    const int quad  = lane >> 4;
    const int mrow  = w & 1;
    const int nt    = w >> 1;
    const int myrow = 16 * mrow + m_in;
    const float rs  = rinv[myrow];

    bf16x8 wfrag[2];
#pragma unroll
    for (int kk = 0; kk < 2; ++kk)
#pragma unroll
        for (int j = 0; j < 8; ++j)
            wfrag[kk][j] = f2bf(fire_lds[myrow][quad * 8 + j + kk * 32] * rs);

    f32x4 acc = (f32x4){0.f, 0.f, 0.f, 0.f};
    const f32x4 z4 = (f32x4){0.f, 0.f, 0.f, 0.f};
    const int xoff = 16 * mrow + quad * 4;

    for (int f = 0; f < F; ++f) {
        bf16x8 bf0 = Wp[f * 512 + nt * 128 + lane];
        bf16x8 bf1 = Wp[f * 512 + nt * 128 + 64 + lane];
        f32x4 U = __builtin_amdgcn_mfma_f32_16x16x32_bf16(wfrag[0], bf0, z4, 0, 0, 0);
        U = __builtin_amdgcn_mfma_f32_16x16x32_bf16(wfrag[1], bf1, U, 0, 0, 0);
        f32x4 xv = *(const f32x4*)(&xt[f][xoff]);
#pragma unroll
        for (int reg = 0; reg < 4; ++reg)
            acc[reg] = __builtin_fmaf(xv[reg], U[reg], acc[reg]);
    }

    // bias column (Xa[:,64] = 1): acc += w @ B_64
    {
        bf16x8 bf0 = Wp[64 * 512 + nt * 128 + lane];
        bf16x8 bf1 = Wp[64 * 512 + nt * 128 + 64 + lane];
        f32x4 U = __builtin_amdgcn_mfma_f32_16x16x32_bf16(wfrag[0], bf0, z4, 0, 0, 0);
        U = __builtin_amdgcn_mfma_f32_16x16x32_bf16(wfrag[1], bf1, U, 0, 0, 0);
#pragma unroll
        for (int reg = 0; reg < 4; ++reg)
            acc[reg] += U[reg];
    }

    // epilogue: D[row][col], row = 16*mrow + quad*4 + reg, col = nt*16 + m_in
#pragma unroll
    for (int reg = 0; reg < 4; ++reg) {
        int row = b0 + 16 * mrow + quad * 4 + reg;
        out[(size_t)row * 64 + nt * 16 + m_in] = acc[reg];
    }
}

extern "C" void kernel_launch(void* const* d_in, const int* in_sizes, int n_in,
                              void* d_out, int out_size, void* d_ws, size_t ws_size,
                              hipStream_t stream) {
    const float* X    = (const float*)d_in[0];
    const float* tt   = (const float*)d_in[1];
    const float* mean = (const float*)d_in[2];
    const float* std_ = (const float*)d_in[3];
    const float* W    = (const float*)d_in[4];
    float* out = (float*)d_out;

    // workspace: prm (float4 x 4096 = 64 KiB) | Wpk (bf16 x 65*4096 = 520 KiB)
    float* prm = (float*)d_ws;
    unsigned short* Wpk = (unsigned short*)((char*)d_ws + 65536);

    fq_prep<<<146, 256, 0, stream>>>(tt, mean, std_, W, prm, Wpk);

    const int nblocks = 32768 / BLOCK_B;  // 1024
    fq_main<<<nblocks, 512, 0, stream>>>(X, (const float4*)prm,
                                         (const bf16x8*)Wpk, out);
}